// Round 12
// baseline (192.897 us; speedup 1.0000x reference)
//
#include <hip/hip_runtime.h>

#define SEQ   4096
#define EMBED 256
#define HEADS 8
#define HDIM  32
#define BH    16      // B * HEADS
#define NROW  8192    // B * SEQ

typedef __bf16 bf16;
typedef bf16  bf16x8 __attribute__((ext_vector_type(8)));
typedef bf16  bf16x4 __attribute__((ext_vector_type(4)));
typedef float f32x4  __attribute__((ext_vector_type(4)));

static __device__ __forceinline__ bf16x4 cvt4(float4 v) {
  bf16x4 r;
  r.x = (bf16)v.x; r.y = (bf16)v.y; r.z = (bf16)v.z; r.w = (bf16)v.w;
  return r;
}

static __device__ __forceinline__ float fast_exp2(float x) {
  float r;
  asm volatile("v_exp_f32 %0, %1" : "=v"(r) : "v"(x));
  return r;
}

// ---------------------------------------------------------------------------
// Merged QKV projection (grid.y selects q/k/v).  Unchanged from the passing
// round-11 build (double-buffered K-loop, __sincosf).
// ---------------------------------------------------------------------------
__global__ __launch_bounds__(256, 4) void proj_kernel(
    const float* __restrict__ qx, const float* __restrict__ kx, const float* __restrict__ vx,
    const float* __restrict__ Wq, const float* __restrict__ bq,
    const float* __restrict__ Wk, const float* __restrict__ bk,
    const float* __restrict__ Wv, const float* __restrict__ bv,
    bf16* __restrict__ qh, bf16* __restrict__ kh, bf16* __restrict__ vt,
    float qscale)
{
  __shared__ alignas(16) bf16 As[2][64][72];
  __shared__ alignas(16) bf16 Bs[2][64][72];
  const int z = blockIdx.z;
  const float* X    = (z == 0) ? qx : (z == 1) ? kx : vx;
  const float* W    = (z == 0) ? Wq : (z == 1) ? Wk : Wv;
  const float* bias = (z == 0) ? bq : (z == 1) ? bk : bv;

  const int tid  = threadIdx.x;
  const int wave = tid >> 6;
  const int lane = tid & 63;
  const int quad = lane >> 4;
  const int l16  = lane & 15;
  const int row0 = blockIdx.x * 64;
  const int col0 = blockIdx.y * 64;

  // per-thread staging coordinates (fixed across K-steps)
  const int sr = tid >> 4;            // row within tile (p adds 16 rows)
  const int sc = (tid & 15) * 4;      // float4 column offset

  f32x4 acc[4] = { {0.f,0.f,0.f,0.f},{0.f,0.f,0.f,0.f},
                   {0.f,0.f,0.f,0.f},{0.f,0.f,0.f,0.f} };

  // ---- prologue: stage K-tile 0 into buf0 ----
#pragma unroll
  for (int p = 0; p < 4; ++p) {
    int r = p * 16 + sr;
    float4 av = *(const float4*)&X[(size_t)(row0 + r) * EMBED + sc];
    *(bf16x4*)&As[0][r][sc] = cvt4(av);
    float4 wv = *(const float4*)&W[(size_t)(col0 + r) * EMBED + sc];
    *(bf16x4*)&Bs[0][r][sc] = cvt4(wv);
  }
  __syncthreads();

#pragma unroll
  for (int it = 0; it < 4; ++it) {
    const int cur = it & 1;

    // ---- issue next K-tile's global loads FIRST (hide under MFMA) ----
    float4 pav[4], pwv[4];
    if (it < 3) {
      const int kn = (it + 1) * 64;
#pragma unroll
      for (int p = 0; p < 4; ++p) {
        int r = p * 16 + sr;
        pav[p] = *(const float4*)&X[(size_t)(row0 + r) * EMBED + kn + sc];
        pwv[p] = *(const float4*)&W[(size_t)(col0 + r) * EMBED + kn + sc];
      }
    }

    // ---- compute current tile from LDS ----
#pragma unroll
    for (int kk = 0; kk < 2; ++kk) {
      bf16x8 a = *(const bf16x8*)&As[cur][wave * 16 + l16][kk * 32 + quad * 8];
#pragma unroll
      for (int nt = 0; nt < 4; ++nt) {
        bf16x8 b = *(const bf16x8*)&Bs[cur][nt * 16 + l16][kk * 32 + quad * 8];
        acc[nt] = __builtin_amdgcn_mfma_f32_16x16x32_bf16(a, b, acc[nt], 0, 0, 0);
      }
    }

    // ---- write staged regs into the other buffer, single barrier ----
    if (it < 3) {
#pragma unroll
      for (int p = 0; p < 4; ++p) {
        int r = p * 16 + sr;
        *(bf16x4*)&As[cur ^ 1][r][sc] = cvt4(pav[p]);
        *(bf16x4*)&Bs[cur ^ 1][r][sc] = cvt4(pwv[p]);
      }
      __syncthreads();
    }
  }

  if (z < 2) {
    bf16* dst = z ? kh : qh;
    const float out_scale = z ? 1.0f : qscale;
#pragma unroll
    for (int nt = 0; nt < 4; ++nt) {
#pragma unroll
      for (int r = 0; r < 4; ++r) {
        int row = row0 + wave * 16 + quad * 4 + r;   // n = b*SEQ + l
        int col = col0 + nt * 16 + l16;              // e = h*32 + d
        float val = acc[nt][r] + bias[col];
        int l = row & (SEQ - 1);
        {
          float other = __shfl_xor(val, 1);          // partner holds d^1
          int d = col & (HDIM - 1);
          int j = d >> 1;                            // freq index 0..15
          float fr = exp2f(-1.6609640474436813f * (float)(j & 7));
          float t  = (j < 8) ? (float)(l & 63) : (float)(l >> 6);
          float ang = t * fr;
          float sv, cv;
          __sincosf(ang, &sv, &cv);                  // HW v_sin/v_cos
          val = (col & 1) ? (other * sv + val * cv) : (val * cv - other * sv);
        }
        val *= out_scale;
        int b = row >> 12;
        int h = col >> 5;
        int d = col & (HDIM - 1);
        dst[((size_t)((b * HEADS + h) * SEQ + l)) * HDIM + d] = (bf16)val;
      }
    }
  } else {
    // V epilogue: bias, LDS transpose (reuse As[0]), write vt[bh][d][l]
    __syncthreads();                    // all compute reads of As done
#pragma unroll
    for (int nt = 0; nt < 4; ++nt) {
      float bcol = bias[col0 + nt * 16 + l16];
      bf16x4 pk;
      pk.x = (bf16)(acc[nt][0] + bcol);
      pk.y = (bf16)(acc[nt][1] + bcol);
      pk.z = (bf16)(acc[nt][2] + bcol);
      pk.w = (bf16)(acc[nt][3] + bcol);
      *(bf16x4*)&As[0][nt * 16 + l16][wave * 16 + quad * 4] = pk;
    }
    __syncthreads();
    const int e   = tid >> 2;           // 0..63 (col within tile)
    const int seg = tid & 3;            // 16-l chunk
    const int ge  = col0 + e;
    const int hh  = ge >> 5;
    const int d   = ge & (HDIM - 1);
    const int bidx = row0 >> 12;
    const int l0   = row0 & (SEQ - 1);
    size_t dstbase = ((size_t)(bidx * HEADS + hh) * HDIM + d) * SEQ + l0 + seg * 16;
    bf16x8 t0 = *(const bf16x8*)&As[0][e][seg * 16];
    bf16x8 t1 = *(const bf16x8*)&As[0][e][seg * 16 + 8];
    *(bf16x8*)&vt[dstbase]     = t0;
    *(bf16x8*)&vt[dstbase + 8] = t1;
  }
}

// ---------------------------------------------------------------------------
// Flash attention v11 — occupancy fix: 4-wave / 256-thread blocks, grid 1024.
//  Evidence (round 10/11 counters): attn is grid-capped at 2 blocks/CU
//  (512 blocks / 256 CU), OccupancyPercent 36.7% while LDS/threads allow 4
//  blocks/CU.  With only 2 barrier-locked blocks per CU, every __syncthreads
//  + Pa drain idles ~half the CU (~45% neither-MFMA-nor-VALU).
//  CHANGE: block = 64 q-rows (4 waves x 16), grid = 1024 -> 4 blocks/CU;
//  independent blocks overlap each other's barrier waits.  NO inner-loop
//  semantic change: per-wave compute loop is byte-for-byte v8's (passing);
//  staging is byte-for-byte v9's 128K+128V/2x16B pattern (passing).
//  K/V L2 traffic doubles (256->512 MB) — still 4x under the pre-v8 wall.
// ---------------------------------------------------------------------------
__global__ __launch_bounds__(256, 4) void attn_kernel(
    const bf16* __restrict__ Q, const bf16* __restrict__ K,
    const bf16* __restrict__ Vt, bf16* __restrict__ H)
{
  __shared__ alignas(16) bf16 Ks[2][4][64][8];   // [buf][frag][slot][8]
  __shared__ alignas(16) bf16 Vs[2][4][64][8];   // [buf][frag][slot][8]
  __shared__ alignas(16) bf16 Pa[4][16][72];     // per-wave P tile [q][key]

  const int tid  = threadIdx.x;
  const int wave = tid >> 6;
  const int lane = tid & 63;
  const int quad = lane >> 4;
  const int l16  = lane & 15;

  const int id = blockIdx.x;                     // 0..1023
  const int bh = ((id & 7) << 1) | (id >> 9);    // XCD-local heads (2/XCD)
  const int q0 = ((id >> 3) & 63) * 64 + wave * 16;   // wave's 16 q rows

  const bf16* Qg = Q  + (size_t)bh * SEQ * HDIM;
  const bf16* Kg = K  + (size_t)bh * SEQ * HDIM;
  const bf16* Vg = Vt + (size_t)bh * HDIM * SEQ;

  // Q fragment (B-operand): n = l16 (q row), k = quad*8+j (dim)
  bf16x8 qf = *(const bf16x8*)&Qg[(size_t)(q0 + l16) * HDIM + quad * 8];

  f32x4 o0 = {0.f,0.f,0.f,0.f};
  f32x4 o1 = {0.f,0.f,0.f,0.f};
  float lsum = 0.f;

  // ---- staging roles (verbatim from passing v9): threads 0-127 stage K,
  //      128-255 stage V; each thread two 16B global loads + two
  //      ds_write_b128 per tile.
  const bool isK = tid < 128;
  const int  tt  = tid & 127;
  const bf16* sbase;
  size_t sstep, soff2;
  bf16* d0;
  if (isK) {
    const int r  = tt >> 2;            // key row in tile 0..31 (+32 pair)
    const int qq = tt & 3;             // dim quarter
    sbase = Kg + (size_t)r * HDIM + qq * 8;
    sstep = (size_t)64 * HDIM;         // next tile: +64 key rows
    soff2 = (size_t)32 * HDIM;         // pair element: +32 key rows
    d0 = &Ks[0][r >> 4][qq * 16 + (r & 15)][0];
  } else {
    const int d  = tt >> 3;            // dim row 0..15 (+16 pair)
    const int sg = tt & 7;             // key segment (8 keys)
    sbase = Vg + (size_t)d * SEQ + sg * 8;
    sstep = 64;                        // next tile: +64 keys
    soff2 = (size_t)16 * SEQ;          // pair element: +16 dim rows
    d0 = &Vs[0][((d >> 4) << 1) | (sg >> 2)][(sg & 3) * 16 + (d & 15)][0];
  }
  bf16* d0b = d0 + 1024;               // pair slot (frag index +2)
  bf16* d1  = d0 + 2048;               // buf1 slice
  bf16* d1b = d1 + 1024;

  const f32x4 minit = {-12.f,-12.f,-12.f,-12.f};   // fixed softmax max

  // ---- prologue: stage tile 0 into buf0 ----
  *(bf16x8*)d0  = *(const bf16x8*)sbase;
  *(bf16x8*)d0b = *(const bf16x8*)&sbase[soff2];
  __syncthreads();

  for (int t = 0; t < 64; ++t) {
    const int cur = t & 1;
    const int tn  = (t < 63) ? t + 1 : 63;   // last iter: harmless re-stage
    // ---- issue next-tile global loads FIRST (complete under compute) ----
    bf16x8 g0 = *(const bf16x8*)&sbase[(size_t)tn * sstep];
    bf16x8 g1 = *(const bf16x8*)&sbase[(size_t)tn * sstep + soff2];

    const bf16* KT = &Ks[cur][0][0][0];
    const bf16* VT = &Vs[cur][0][0][0];

    // ---- K fragments from LDS (linear per lane) ----
    bf16x8 kf0 = *(const bf16x8*)&KT[(0 * 64 + lane) * 8];
    bf16x8 kf1 = *(const bf16x8*)&KT[(1 * 64 + lane) * 8];
    bf16x8 kf2 = *(const bf16x8*)&KT[(2 * 64 + lane) * 8];
    bf16x8 kf3 = *(const bf16x8*)&KT[(3 * 64 + lane) * 8];

    // ---- S^T = K Q^T - 12 : col = q (l16), rows = 4 consecutive keys ----
    f32x4 s[4];
    s[0] = __builtin_amdgcn_mfma_f32_16x16x32_bf16(kf0, qf, minit, 0, 0, 0);
    s[1] = __builtin_amdgcn_mfma_f32_16x16x32_bf16(kf1, qf, minit, 0, 0, 0);
    s[2] = __builtin_amdgcn_mfma_f32_16x16x32_bf16(kf2, qf, minit, 0, 0, 0);
    s[3] = __builtin_amdgcn_mfma_f32_16x16x32_bf16(kf3, qf, minit, 0, 0, 0);

    // ---- V^T fragments from LDS ----
    bf16x8 vf0 = *(const bf16x8*)&VT[(0 * 64 + lane) * 8];
    bf16x8 vf1 = *(const bf16x8*)&VT[(1 * 64 + lane) * 8];
    bf16x8 vf2 = *(const bf16x8*)&VT[(2 * 64 + lane) * 8];
    bf16x8 vf3 = *(const bf16x8*)&VT[(3 * 64 + lane) * 8];

    // ---- softmax numerators + packed P store + per-lane row-sum ----
    //      (textually identical to the verified v8 round-trip)
#pragma unroll
    for (int nt = 0; nt < 4; ++nt) {
      float p0 = fast_exp2(s[nt][0]);
      float p1 = fast_exp2(s[nt][1]);
      float p2 = fast_exp2(s[nt][2]);
      float p3 = fast_exp2(s[nt][3]);
      lsum += (p0 + p1) + (p2 + p3);
      bf16x4 pk;
      pk.x = (bf16)p0; pk.y = (bf16)p1; pk.z = (bf16)p2; pk.w = (bf16)p3;
      *(bf16x4*)&Pa[wave][l16][nt * 16 + quad * 4] = pk;   // ds_write_b64
    }

    // wave-internal LDS round trip (DS in-order per wave; drain before read)
    asm volatile("s_waitcnt lgkmcnt(0)" ::: "memory");

    // ---- O += P V : A = P[q][key], B = V^T[d][key] ----
    bf16x8 pf0 = *(const bf16x8*)&Pa[wave][l16][quad * 8];
    bf16x8 pf1 = *(const bf16x8*)&Pa[wave][l16][32 + quad * 8];
    o0 = __builtin_amdgcn_mfma_f32_16x16x32_bf16(pf0, vf0, o0, 0, 0, 0);
    o0 = __builtin_amdgcn_mfma_f32_16x16x32_bf16(pf1, vf1, o0, 0, 0, 0);
    o1 = __builtin_amdgcn_mfma_f32_16x16x32_bf16(pf0, vf2, o1, 0, 0, 0);
    o1 = __builtin_amdgcn_mfma_f32_16x16x32_bf16(pf1, vf3, o1, 0, 0, 0);

    // ---- write staged data into the other buffer, then fence the tile ----
    *(bf16x8*)(cur ? d0  : d1 ) = g0;
    *(bf16x8*)(cur ? d0b : d1b) = g1;
    __syncthreads();
  }

  // ---- reduce row-sums across quads: lsum(lane) = total for q = l16 ----
  lsum += __shfl_xor(lsum, 16);
  lsum += __shfl_xor(lsum, 32);

  const int b = bh >> 3;
  const int h = bh & 7;
#pragma unroll
  for (int r = 0; r < 4; ++r) {
    float tot  = __shfl(lsum, quad * 4 + r);   // lane with l16 == quad*4+r
    float invr = 1.0f / tot;
    int   qg   = q0 + quad * 4 + r;
    size_t base = ((size_t)(b * SEQ + qg)) * EMBED + h * HDIM;
    H[base + l16]      = (bf16)(o0[r] * invr);
    H[base + 16 + l16] = (bf16)(o1[r] * invr);
  }
}

// ---------------------------------------------------------------------------
// Output projection: out = H @ Wo^T + bo   (fp32 out)  — unchanged
// ---------------------------------------------------------------------------
__global__ __launch_bounds__(256) void out_proj_kernel(
    const bf16* __restrict__ Hm, const float* __restrict__ W,
    const float* __restrict__ bias, float* __restrict__ out)
{
  __shared__ alignas(16) bf16 As[64][72];
  __shared__ alignas(16) bf16 Bs[64][72];
  const int tid  = threadIdx.x;
  const int wave = tid >> 6;
  const int lane = tid & 63;
  const int quad = lane >> 4;
  const int l16  = lane & 15;
  const int row0 = blockIdx.x * 64;
  const int col0 = blockIdx.y * 64;

  f32x4 acc[4] = { {0.f,0.f,0.f,0.f},{0.f,0.f,0.f,0.f},
                   {0.f,0.f,0.f,0.f},{0.f,0.f,0.f,0.f} };

  for (int k0 = 0; k0 < EMBED; k0 += 64) {
#pragma unroll
    for (int p = 0; p < 2; ++p) {       // A: bf16 loads
      int f = p * 256 + tid;
      int r = f >> 3;
      int c = (f & 7) * 8;
      *(bf16x8*)&As[r][c] = *(const bf16x8*)&Hm[(size_t)(row0 + r) * EMBED + k0 + c];
    }
#pragma unroll
    for (int p = 0; p < 4; ++p) {       // B: fp32 -> bf16
      int f = p * 256 + tid;
      int r = f >> 4;
      int c = (f & 15) * 4;
      float4 wv = *(const float4*)&W[(size_t)(col0 + r) * EMBED + k0 + c];
      *(bf16x4*)&Bs[r][c] = cvt4(wv);
    }
    __syncthreads();
#pragma unroll
    for (int kk = 0; kk < 2; ++kk) {
      bf16x8 a = *(const bf16x8*)&As[wave * 16 + l16][kk * 32 + quad * 8];
#pragma unroll
      for (int nt = 0; nt < 4; ++nt) {
        bf16x8 b = *(const bf16x8*)&Bs[nt * 16 + l16][kk * 32 + quad * 8];
        acc[nt] = __builtin_amdgcn_mfma_f32_16x16x32_bf16(a, b, acc[nt], 0, 0, 0);
      }
    }
    __syncthreads();
  }

#pragma unroll
  for (int nt = 0; nt < 4; ++nt) {
#pragma unroll
    for (int r = 0; r < 4; ++r) {
      int row = row0 + wave * 16 + quad * 4 + r;
      int col = col0 + nt * 16 + l16;
      out[(size_t)row * EMBED + col] = acc[nt][r] + bias[col];
    }
  }
}

// ---------------------------------------------------------------------------
extern "C" void kernel_launch(void* const* d_in, const int* in_sizes, int n_in,
                              void* d_out, int out_size, void* d_ws, size_t ws_size,
                              hipStream_t stream) {
  (void)in_sizes; (void)n_in; (void)out_size; (void)ws_size;
  const float* q  = (const float*)d_in[0];
  const float* k  = (const float*)d_in[1];
  const float* v  = (const float*)d_in[2];
  const float* Wq = (const float*)d_in[3];
  const float* bq = (const float*)d_in[4];
  const float* Wk = (const float*)d_in[5];
  const float* bk = (const float*)d_in[6];
  const float* Wv = (const float*)d_in[7];
  const float* bv = (const float*)d_in[8];
  const float* Wo = (const float*)d_in[9];
  const float* bo = (const float*)d_in[10];
  float* out = (float*)d_out;

  const size_t headElems = (size_t)BH * SEQ * HDIM;   // 2,097,152
  bf16* qh = (bf16*)d_ws;
  bf16* kh = qh + headElems;
  bf16* vt = kh + headElems;                          // [BH][HDIM][SEQ]
  bf16* Hm = vt + headElems;                          // [8192][256]

  // Q pre-scale: (1/sqrt(32)) * log2(e) -> softmax in exp2 domain.
  const float qs = 0.2550436604f;

  proj_kernel<<<dim3(128, 4, 3), dim3(256), 0, stream>>>(q, k, v, Wq, bq, Wk, bk,
                                                         Wv, bv, qh, kh, vt, qs);
  attn_kernel<<<dim3(1024), dim3(256), 0, stream>>>(qh, kh, vt, Hm);
  out_proj_kernel<<<dim3(128, 4), dim3(256), 0, stream>>>(Hm, Wo, bo, out);
}

// Round 13
// 167.542 us; speedup vs baseline: 1.1513x; 1.1513x over previous
//
#include <hip/hip_runtime.h>

#define SEQ   4096
#define EMBED 256
#define HEADS 8
#define HDIM  32
#define BH    16      // B * HEADS
#define NROW  8192    // B * SEQ

typedef __bf16 bf16;
typedef bf16  bf16x8 __attribute__((ext_vector_type(8)));
typedef bf16  bf16x4 __attribute__((ext_vector_type(4)));
typedef float f32x4  __attribute__((ext_vector_type(4)));

static __device__ __forceinline__ bf16x4 cvt4(float4 v) {
  bf16x4 r;
  r.x = (bf16)v.x; r.y = (bf16)v.y; r.z = (bf16)v.z; r.w = (bf16)v.w;
  return r;
}

static __device__ __forceinline__ float fast_exp2(float x) {
  float r;
  asm volatile("v_exp_f32 %0, %1" : "=v"(r) : "v"(x));
  return r;
}

// ---------------------------------------------------------------------------
// Merged QKV projection (grid.y selects q/k/v).  Unchanged from the passing
// round-11 build (double-buffered K-loop, __sincosf).
// ---------------------------------------------------------------------------
__global__ __launch_bounds__(256, 4) void proj_kernel(
    const float* __restrict__ qx, const float* __restrict__ kx, const float* __restrict__ vx,
    const float* __restrict__ Wq, const float* __restrict__ bq,
    const float* __restrict__ Wk, const float* __restrict__ bk,
    const float* __restrict__ Wv, const float* __restrict__ bv,
    bf16* __restrict__ qh, bf16* __restrict__ kh, bf16* __restrict__ vt,
    float qscale)
{
  __shared__ alignas(16) bf16 As[2][64][72];
  __shared__ alignas(16) bf16 Bs[2][64][72];
  const int z = blockIdx.z;
  const float* X    = (z == 0) ? qx : (z == 1) ? kx : vx;
  const float* W    = (z == 0) ? Wq : (z == 1) ? Wk : Wv;
  const float* bias = (z == 0) ? bq : (z == 1) ? bk : bv;

  const int tid  = threadIdx.x;
  const int wave = tid >> 6;
  const int lane = tid & 63;
  const int quad = lane >> 4;
  const int l16  = lane & 15;
  const int row0 = blockIdx.x * 64;
  const int col0 = blockIdx.y * 64;

  // per-thread staging coordinates (fixed across K-steps)
  const int sr = tid >> 4;            // row within tile (p adds 16 rows)
  const int sc = (tid & 15) * 4;      // float4 column offset

  f32x4 acc[4] = { {0.f,0.f,0.f,0.f},{0.f,0.f,0.f,0.f},
                   {0.f,0.f,0.f,0.f},{0.f,0.f,0.f,0.f} };

  // ---- prologue: stage K-tile 0 into buf0 ----
#pragma unroll
  for (int p = 0; p < 4; ++p) {
    int r = p * 16 + sr;
    float4 av = *(const float4*)&X[(size_t)(row0 + r) * EMBED + sc];
    *(bf16x4*)&As[0][r][sc] = cvt4(av);
    float4 wv = *(const float4*)&W[(size_t)(col0 + r) * EMBED + sc];
    *(bf16x4*)&Bs[0][r][sc] = cvt4(wv);
  }
  __syncthreads();

#pragma unroll
  for (int it = 0; it < 4; ++it) {
    const int cur = it & 1;

    // ---- issue next K-tile's global loads FIRST (hide under MFMA) ----
    float4 pav[4], pwv[4];
    if (it < 3) {
      const int kn = (it + 1) * 64;
#pragma unroll
      for (int p = 0; p < 4; ++p) {
        int r = p * 16 + sr;
        pav[p] = *(const float4*)&X[(size_t)(row0 + r) * EMBED + kn + sc];
        pwv[p] = *(const float4*)&W[(size_t)(col0 + r) * EMBED + kn + sc];
      }
    }

    // ---- compute current tile from LDS ----
#pragma unroll
    for (int kk = 0; kk < 2; ++kk) {
      bf16x8 a = *(const bf16x8*)&As[cur][wave * 16 + l16][kk * 32 + quad * 8];
#pragma unroll
      for (int nt = 0; nt < 4; ++nt) {
        bf16x8 b = *(const bf16x8*)&Bs[cur][nt * 16 + l16][kk * 32 + quad * 8];
        acc[nt] = __builtin_amdgcn_mfma_f32_16x16x32_bf16(a, b, acc[nt], 0, 0, 0);
      }
    }

    // ---- write staged regs into the other buffer, single barrier ----
    if (it < 3) {
#pragma unroll
      for (int p = 0; p < 4; ++p) {
        int r = p * 16 + sr;
        *(bf16x4*)&As[cur ^ 1][r][sc] = cvt4(pav[p]);
        *(bf16x4*)&Bs[cur ^ 1][r][sc] = cvt4(pwv[p]);
      }
      __syncthreads();
    }
  }

  if (z < 2) {
    bf16* dst = z ? kh : qh;
    const float out_scale = z ? 1.0f : qscale;
#pragma unroll
    for (int nt = 0; nt < 4; ++nt) {
#pragma unroll
      for (int r = 0; r < 4; ++r) {
        int row = row0 + wave * 16 + quad * 4 + r;   // n = b*SEQ + l
        int col = col0 + nt * 16 + l16;              // e = h*32 + d
        float val = acc[nt][r] + bias[col];
        int l = row & (SEQ - 1);
        {
          float other = __shfl_xor(val, 1);          // partner holds d^1
          int d = col & (HDIM - 1);
          int j = d >> 1;                            // freq index 0..15
          float fr = exp2f(-1.6609640474436813f * (float)(j & 7));
          float t  = (j < 8) ? (float)(l & 63) : (float)(l >> 6);
          float ang = t * fr;
          float sv, cv;
          __sincosf(ang, &sv, &cv);                  // HW v_sin/v_cos
          val = (col & 1) ? (other * sv + val * cv) : (val * cv - other * sv);
        }
        val *= out_scale;
        int b = row >> 12;
        int h = col >> 5;
        int d = col & (HDIM - 1);
        dst[((size_t)((b * HEADS + h) * SEQ + l)) * HDIM + d] = (bf16)val;
      }
    }
  } else {
    // V epilogue: bias, LDS transpose (reuse As[0]), write vt[bh][d][l]
    __syncthreads();                    // all compute reads of As done
#pragma unroll
    for (int nt = 0; nt < 4; ++nt) {
      float bcol = bias[col0 + nt * 16 + l16];
      bf16x4 pk;
      pk.x = (bf16)(acc[nt][0] + bcol);
      pk.y = (bf16)(acc[nt][1] + bcol);
      pk.z = (bf16)(acc[nt][2] + bcol);
      pk.w = (bf16)(acc[nt][3] + bcol);
      *(bf16x4*)&As[0][nt * 16 + l16][wave * 16 + quad * 4] = pk;
    }
    __syncthreads();
    const int e   = tid >> 2;           // 0..63 (col within tile)
    const int seg = tid & 3;            // 16-l chunk
    const int ge  = col0 + e;
    const int hh  = ge >> 5;
    const int d   = ge & (HDIM - 1);
    const int bidx = row0 >> 12;
    const int l0   = row0 & (SEQ - 1);
    size_t dstbase = ((size_t)(bidx * HEADS + hh) * HDIM + d) * SEQ + l0 + seg * 16;
    bf16x8 t0 = *(const bf16x8*)&As[0][e][seg * 16];
    bf16x8 t1 = *(const bf16x8*)&As[0][e][seg * 16 + 8];
    *(bf16x8*)&vt[dstbase]     = t0;
    *(bf16x8*)&vt[dstbase + 8] = t1;
  }
}

// ---------------------------------------------------------------------------
// Flash attention v8 — byte-identical to the round-7/10/11 PASSING kernel
// (attn 75.7-76.7 us, MfmaUtil ~18.5%).  Round-12's 4-wave/grid-1024 variant
// REGRESSED (100 us: occupancy unchanged, staging overhead and bank
// conflicts doubled) — reverted.
// ---------------------------------------------------------------------------
__global__ __launch_bounds__(512, 4) void attn_kernel(
    const bf16* __restrict__ Q, const bf16* __restrict__ K,
    const bf16* __restrict__ Vt, bf16* __restrict__ H)
{
  __shared__ alignas(16) bf16 Ks[2][4][64][8];   // [buf][frag][lane][8]
  __shared__ alignas(16) bf16 Vs[2][4][64][8];   // [buf][frag][lane][8]
  __shared__ alignas(16) bf16 Pa[8][16][72];     // per-wave P tile [q][key]

  const int tid  = threadIdx.x;
  const int wave = tid >> 6;
  const int lane = tid & 63;
  const int quad = lane >> 4;
  const int l16  = lane & 15;

  const int id = blockIdx.x;                     // 0..511
  const int bh = ((id & 7) << 1) | (id >> 8);    // XCD-local heads (2/XCD)
  const int q0 = ((id >> 3) & 31) * 128 + wave * 16;  // wave's 16 q rows

  const bf16* Qg = Q  + (size_t)bh * SEQ * HDIM;
  const bf16* Kg = K  + (size_t)bh * SEQ * HDIM;
  const bf16* Vg = Vt + (size_t)bh * HDIM * SEQ;

  // Q fragment (B-operand): n = l16 (q row), k = quad*8+j (dim)
  bf16x8 qf = *(const bf16x8*)&Qg[(size_t)(q0 + l16) * HDIM + quad * 8];

  f32x4 o0 = {0.f,0.f,0.f,0.f};
  f32x4 o1 = {0.f,0.f,0.f,0.f};
  float lsum = 0.f;

  // ---- staging role: threads 0-255 stage K, 256-511 stage V.
  //      Each thread: one 16B global load + one ds_write_b128 per tile.
  const bool isK = tid < 256;
  const int  tt  = tid & 255;
  const bf16* sbase;
  size_t sstep;
  bf16* d0;
  if (isK) {
    const int r  = tt >> 2;            // key row in tile 0..63
    const int qq = tt & 3;             // dim quarter
    sbase = Kg + (size_t)r * HDIM + qq * 8;
    sstep = (size_t)64 * HDIM;         // next tile: +64 key rows
    d0 = &Ks[0][r >> 4][qq * 16 + (r & 15)][0];
  } else {
    const int d  = tt >> 3;            // dim row 0..31
    const int sg = tt & 7;             // key segment (8 keys)
    sbase = Vg + (size_t)d * SEQ + sg * 8;
    sstep = 64;                        // next tile: +64 keys
    d0 = &Vs[0][((d >> 4) << 1) | (sg >> 2)][(sg & 3) * 16 + (d & 15)][0];
  }
  bf16* d1 = d0 + 4 * 64 * 8;          // buf1 slice of the same array

  const f32x4 minit = {-12.f,-12.f,-12.f,-12.f};   // fixed softmax max

  // ---- prologue: stage tile 0 into buf0 ----
  *(bf16x8*)d0 = *(const bf16x8*)sbase;
  __syncthreads();

  for (int t = 0; t < 64; ++t) {
    const int cur = t & 1;
    const int tn  = (t < 63) ? t + 1 : 63;   // last iter: harmless re-stage
    // ---- issue next-tile global load FIRST (completes under compute) ----
    bf16x8 g = *(const bf16x8*)&sbase[(size_t)tn * sstep];

    const bf16* KT = &Ks[cur][0][0][0];
    const bf16* VT = &Vs[cur][0][0][0];

    // ---- K fragments from LDS (linear per lane: zero bank conflict) ----
    bf16x8 kf0 = *(const bf16x8*)&KT[(0 * 64 + lane) * 8];
    bf16x8 kf1 = *(const bf16x8*)&KT[(1 * 64 + lane) * 8];
    bf16x8 kf2 = *(const bf16x8*)&KT[(2 * 64 + lane) * 8];
    bf16x8 kf3 = *(const bf16x8*)&KT[(3 * 64 + lane) * 8];

    // ---- S^T = K Q^T - 12 : col = q (l16), rows = 4 consecutive keys ----
    f32x4 s[4];
    s[0] = __builtin_amdgcn_mfma_f32_16x16x32_bf16(kf0, qf, minit, 0, 0, 0);
    s[1] = __builtin_amdgcn_mfma_f32_16x16x32_bf16(kf1, qf, minit, 0, 0, 0);
    s[2] = __builtin_amdgcn_mfma_f32_16x16x32_bf16(kf2, qf, minit, 0, 0, 0);
    s[3] = __builtin_amdgcn_mfma_f32_16x16x32_bf16(kf3, qf, minit, 0, 0, 0);

    // ---- V^T fragments from LDS ----
    bf16x8 vf0 = *(const bf16x8*)&VT[(0 * 64 + lane) * 8];
    bf16x8 vf1 = *(const bf16x8*)&VT[(1 * 64 + lane) * 8];
    bf16x8 vf2 = *(const bf16x8*)&VT[(2 * 64 + lane) * 8];
    bf16x8 vf3 = *(const bf16x8*)&VT[(3 * 64 + lane) * 8];

    // ---- softmax numerators + packed P store + per-lane row-sum ----
    //      (textually identical to the verified v3/v5 round-trip)
#pragma unroll
    for (int nt = 0; nt < 4; ++nt) {
      float p0 = fast_exp2(s[nt][0]);
      float p1 = fast_exp2(s[nt][1]);
      float p2 = fast_exp2(s[nt][2]);
      float p3 = fast_exp2(s[nt][3]);
      lsum += (p0 + p1) + (p2 + p3);
      bf16x4 pk;
      pk.x = (bf16)p0; pk.y = (bf16)p1; pk.z = (bf16)p2; pk.w = (bf16)p3;
      *(bf16x4*)&Pa[wave][l16][nt * 16 + quad * 4] = pk;   // ds_write_b64
    }

    // wave-internal LDS round trip (DS in-order per wave; drain before read)
    asm volatile("s_waitcnt lgkmcnt(0)" ::: "memory");

    // ---- O += P V : A = P[q][key], B = V^T[d][key] ----
    bf16x8 pf0 = *(const bf16x8*)&Pa[wave][l16][quad * 8];
    bf16x8 pf1 = *(const bf16x8*)&Pa[wave][l16][32 + quad * 8];
    o0 = __builtin_amdgcn_mfma_f32_16x16x32_bf16(pf0, vf0, o0, 0, 0, 0);
    o0 = __builtin_amdgcn_mfma_f32_16x16x32_bf16(pf1, vf1, o0, 0, 0, 0);
    o1 = __builtin_amdgcn_mfma_f32_16x16x32_bf16(pf0, vf2, o1, 0, 0, 0);
    o1 = __builtin_amdgcn_mfma_f32_16x16x32_bf16(pf1, vf3, o1, 0, 0, 0);

    // ---- write staged data into the other buffer, then fence the tile ----
    *(bf16x8*)(cur ? d0 : d1) = g;
    __syncthreads();
  }

  // ---- reduce row-sums across quads: lsum(lane) = total for q = l16 ----
  lsum += __shfl_xor(lsum, 16);
  lsum += __shfl_xor(lsum, 32);

  const int b = bh >> 3;
  const int h = bh & 7;
#pragma unroll
  for (int r = 0; r < 4; ++r) {
    float tot  = __shfl(lsum, quad * 4 + r);   // lane with l16 == quad*4+r
    float invr = 1.0f / tot;
    int   qg   = q0 + quad * 4 + r;
    size_t base = ((size_t)(b * SEQ + qg)) * EMBED + h * HDIM;
    H[base + l16]      = (bf16)(o0[r] * invr);
    H[base + 16 + l16] = (bf16)(o1[r] * invr);
  }
}

// ---------------------------------------------------------------------------
// Output projection: out = H @ Wo^T + bo   (fp32 out)
//  ROUND-13 CHANGE: double-buffered K-loop, one barrier per K-step — the
//  exact transformation that passed on proj_kernel in round 11.  Old: per
//  K-step {stage -> barrier -> MFMA -> barrier}.  New: prefetch next tile's
//  global loads into regs first, MFMA from buf[cur], write regs to
//  buf[cur^1], single barrier.
// ---------------------------------------------------------------------------
__global__ __launch_bounds__(256, 4) void out_proj_kernel(
    const bf16* __restrict__ Hm, const float* __restrict__ W,
    const float* __restrict__ bias, float* __restrict__ out)
{
  __shared__ alignas(16) bf16 As[2][64][72];
  __shared__ alignas(16) bf16 Bs[2][64][72];
  const int tid  = threadIdx.x;
  const int wave = tid >> 6;
  const int lane = tid & 63;
  const int quad = lane >> 4;
  const int l16  = lane & 15;
  const int row0 = blockIdx.x * 64;
  const int col0 = blockIdx.y * 64;

  // staging coordinates
  const int ar = tid >> 3;            // A: row 0..31 (p adds 32), col (tid&7)*8
  const int ac = (tid & 7) * 8;
  const int br = tid >> 4;            // B: row 0..15 (p adds 16), col (tid&15)*4
  const int bc = (tid & 15) * 4;

  f32x4 acc[4] = { {0.f,0.f,0.f,0.f},{0.f,0.f,0.f,0.f},
                   {0.f,0.f,0.f,0.f},{0.f,0.f,0.f,0.f} };

  // ---- prologue: stage K-tile 0 into buf0 ----
#pragma unroll
  for (int p = 0; p < 2; ++p) {
    int r = p * 32 + ar;
    *(bf16x8*)&As[0][r][ac] = *(const bf16x8*)&Hm[(size_t)(row0 + r) * EMBED + ac];
  }
#pragma unroll
  for (int p = 0; p < 4; ++p) {
    int r = p * 16 + br;
    float4 wv = *(const float4*)&W[(size_t)(col0 + r) * EMBED + bc];
    *(bf16x4*)&Bs[0][r][bc] = cvt4(wv);
  }
  __syncthreads();

#pragma unroll
  for (int it = 0; it < 4; ++it) {
    const int cur = it & 1;

    // ---- issue next K-tile's global loads FIRST (hide under MFMA) ----
    bf16x8 pa[2];
    float4 pw[4];
    if (it < 3) {
      const int kn = (it + 1) * 64;
#pragma unroll
      for (int p = 0; p < 2; ++p) {
        int r = p * 32 + ar;
        pa[p] = *(const bf16x8*)&Hm[(size_t)(row0 + r) * EMBED + kn + ac];
      }
#pragma unroll
      for (int p = 0; p < 4; ++p) {
        int r = p * 16 + br;
        pw[p] = *(const float4*)&W[(size_t)(col0 + r) * EMBED + kn + bc];
      }
    }

    // ---- compute current tile from LDS ----
#pragma unroll
    for (int kk = 0; kk < 2; ++kk) {
      bf16x8 a = *(const bf16x8*)&As[cur][wave * 16 + l16][kk * 32 + quad * 8];
#pragma unroll
      for (int nt = 0; nt < 4; ++nt) {
        bf16x8 b = *(const bf16x8*)&Bs[cur][nt * 16 + l16][kk * 32 + quad * 8];
        acc[nt] = __builtin_amdgcn_mfma_f32_16x16x32_bf16(a, b, acc[nt], 0, 0, 0);
      }
    }

    // ---- write staged regs into the other buffer, single barrier ----
    if (it < 3) {
#pragma unroll
      for (int p = 0; p < 2; ++p) {
        int r = p * 32 + ar;
        *(bf16x8*)&As[cur ^ 1][r][ac] = pa[p];
      }
#pragma unroll
      for (int p = 0; p < 4; ++p) {
        int r = p * 16 + br;
        *(bf16x4*)&Bs[cur ^ 1][r][bc] = cvt4(pw[p]);
      }
      __syncthreads();
    }
  }

#pragma unroll
  for (int nt = 0; nt < 4; ++nt) {
#pragma unroll
    for (int r = 0; r < 4; ++r) {
      int row = row0 + wave * 16 + quad * 4 + r;
      int col = col0 + nt * 16 + l16;
      out[(size_t)row * EMBED + col] = acc[nt][r] + bias[col];
    }
  }
}

// ---------------------------------------------------------------------------
extern "C" void kernel_launch(void* const* d_in, const int* in_sizes, int n_in,
                              void* d_out, int out_size, void* d_ws, size_t ws_size,
                              hipStream_t stream) {
  (void)in_sizes; (void)n_in; (void)out_size; (void)ws_size;
  const float* q  = (const float*)d_in[0];
  const float* k  = (const float*)d_in[1];
  const float* v  = (const float*)d_in[2];
  const float* Wq = (const float*)d_in[3];
  const float* bq = (const float*)d_in[4];
  const float* Wk = (const float*)d_in[5];
  const float* bk = (const float*)d_in[6];
  const float* Wv = (const float*)d_in[7];
  const float* bv = (const float*)d_in[8];
  const float* Wo = (const float*)d_in[9];
  const float* bo = (const float*)d_in[10];
  float* out = (float*)d_out;

  const size_t headElems = (size_t)BH * SEQ * HDIM;   // 2,097,152
  bf16* qh = (bf16*)d_ws;
  bf16* kh = qh + headElems;
  bf16* vt = kh + headElems;                          // [BH][HDIM][SEQ]
  bf16* Hm = vt + headElems;                          // [8192][256]

  // Q pre-scale: (1/sqrt(32)) * log2(e) -> softmax in exp2 domain.
  const float qs = 0.2550436604f;

  proj_kernel<<<dim3(128, 4, 3), dim3(256), 0, stream>>>(q, k, v, Wq, bq, Wk, bk,
                                                         Wv, bv, qh, kh, vt, qs);
  attn_kernel<<<dim3(512), dim3(512), 0, stream>>>(qh, kh, vt, Hm);
  out_proj_kernel<<<dim3(128, 4), dim3(256), 0, stream>>>(Hm, Wo, bo, out);
}

// Round 14
// 155.171 us; speedup vs baseline: 1.2431x; 1.0797x over previous
//
#include <hip/hip_runtime.h>

#define SEQ   4096
#define EMBED 256
#define HEADS 8
#define HDIM  32
#define BH    16      // B * HEADS
#define NROW  8192    // B * SEQ

typedef __bf16 bf16;
typedef bf16  bf16x8 __attribute__((ext_vector_type(8)));
typedef bf16  bf16x4 __attribute__((ext_vector_type(4)));
typedef float f32x4  __attribute__((ext_vector_type(4)));

static __device__ __forceinline__ bf16x4 cvt4(float4 v) {
  bf16x4 r;
  r.x = (bf16)v.x; r.y = (bf16)v.y; r.z = (bf16)v.z; r.w = (bf16)v.w;
  return r;
}

static __device__ __forceinline__ float fast_exp2(float x) {
  float r;
  asm volatile("v_exp_f32 %0, %1" : "=v"(r) : "v"(x));
  return r;
}

// ---------------------------------------------------------------------------
// Merged QKV projection (grid.y selects q/k/v).  Unchanged from the passing
// round-13 build (double-buffered K-loop, __sincosf).
// ---------------------------------------------------------------------------
__global__ __launch_bounds__(256, 4) void proj_kernel(
    const float* __restrict__ qx, const float* __restrict__ kx, const float* __restrict__ vx,
    const float* __restrict__ Wq, const float* __restrict__ bq,
    const float* __restrict__ Wk, const float* __restrict__ bk,
    const float* __restrict__ Wv, const float* __restrict__ bv,
    bf16* __restrict__ qh, bf16* __restrict__ kh, bf16* __restrict__ vt,
    float qscale)
{
  __shared__ alignas(16) bf16 As[2][64][72];
  __shared__ alignas(16) bf16 Bs[2][64][72];
  const int z = blockIdx.z;
  const float* X    = (z == 0) ? qx : (z == 1) ? kx : vx;
  const float* W    = (z == 0) ? Wq : (z == 1) ? Wk : Wv;
  const float* bias = (z == 0) ? bq : (z == 1) ? bk : bv;

  const int tid  = threadIdx.x;
  const int wave = tid >> 6;
  const int lane = tid & 63;
  const int quad = lane >> 4;
  const int l16  = lane & 15;
  const int row0 = blockIdx.x * 64;
  const int col0 = blockIdx.y * 64;

  // per-thread staging coordinates (fixed across K-steps)
  const int sr = tid >> 4;            // row within tile (p adds 16 rows)
  const int sc = (tid & 15) * 4;      // float4 column offset

  f32x4 acc[4] = { {0.f,0.f,0.f,0.f},{0.f,0.f,0.f,0.f},
                   {0.f,0.f,0.f,0.f},{0.f,0.f,0.f,0.f} };

  // ---- prologue: stage K-tile 0 into buf0 ----
#pragma unroll
  for (int p = 0; p < 4; ++p) {
    int r = p * 16 + sr;
    float4 av = *(const float4*)&X[(size_t)(row0 + r) * EMBED + sc];
    *(bf16x4*)&As[0][r][sc] = cvt4(av);
    float4 wv = *(const float4*)&W[(size_t)(col0 + r) * EMBED + sc];
    *(bf16x4*)&Bs[0][r][sc] = cvt4(wv);
  }
  __syncthreads();

#pragma unroll
  for (int it = 0; it < 4; ++it) {
    const int cur = it & 1;

    // ---- issue next K-tile's global loads FIRST (hide under MFMA) ----
    float4 pav[4], pwv[4];
    if (it < 3) {
      const int kn = (it + 1) * 64;
#pragma unroll
      for (int p = 0; p < 4; ++p) {
        int r = p * 16 + sr;
        pav[p] = *(const float4*)&X[(size_t)(row0 + r) * EMBED + kn + sc];
        pwv[p] = *(const float4*)&W[(size_t)(col0 + r) * EMBED + kn + sc];
      }
    }

    // ---- compute current tile from LDS ----
#pragma unroll
    for (int kk = 0; kk < 2; ++kk) {
      bf16x8 a = *(const bf16x8*)&As[cur][wave * 16 + l16][kk * 32 + quad * 8];
#pragma unroll
      for (int nt = 0; nt < 4; ++nt) {
        bf16x8 b = *(const bf16x8*)&Bs[cur][nt * 16 + l16][kk * 32 + quad * 8];
        acc[nt] = __builtin_amdgcn_mfma_f32_16x16x32_bf16(a, b, acc[nt], 0, 0, 0);
      }
    }

    // ---- write staged regs into the other buffer, single barrier ----
    if (it < 3) {
#pragma unroll
      for (int p = 0; p < 4; ++p) {
        int r = p * 16 + sr;
        *(bf16x4*)&As[cur ^ 1][r][sc] = cvt4(pav[p]);
        *(bf16x4*)&Bs[cur ^ 1][r][sc] = cvt4(pwv[p]);
      }
      __syncthreads();
    }
  }

  if (z < 2) {
    bf16* dst = z ? kh : qh;
    const float out_scale = z ? 1.0f : qscale;
#pragma unroll
    for (int nt = 0; nt < 4; ++nt) {
#pragma unroll
      for (int r = 0; r < 4; ++r) {
        int row = row0 + wave * 16 + quad * 4 + r;   // n = b*SEQ + l
        int col = col0 + nt * 16 + l16;              // e = h*32 + d
        float val = acc[nt][r] + bias[col];
        int l = row & (SEQ - 1);
        {
          float other = __shfl_xor(val, 1);          // partner holds d^1
          int d = col & (HDIM - 1);
          int j = d >> 1;                            // freq index 0..15
          float fr = exp2f(-1.6609640474436813f * (float)(j & 7));
          float t  = (j < 8) ? (float)(l & 63) : (float)(l >> 6);
          float ang = t * fr;
          float sv, cv;
          __sincosf(ang, &sv, &cv);                  // HW v_sin/v_cos
          val = (col & 1) ? (other * sv + val * cv) : (val * cv - other * sv);
        }
        val *= out_scale;
        int b = row >> 12;
        int h = col >> 5;
        int d = col & (HDIM - 1);
        dst[((size_t)((b * HEADS + h) * SEQ + l)) * HDIM + d] = (bf16)val;
      }
    }
  } else {
    // V epilogue: bias, LDS transpose (reuse As[0]), write vt[bh][d][l]
    __syncthreads();                    // all compute reads of As done
#pragma unroll
    for (int nt = 0; nt < 4; ++nt) {
      float bcol = bias[col0 + nt * 16 + l16];
      bf16x4 pk;
      pk.x = (bf16)(acc[nt][0] + bcol);
      pk.y = (bf16)(acc[nt][1] + bcol);
      pk.z = (bf16)(acc[nt][2] + bcol);
      pk.w = (bf16)(acc[nt][3] + bcol);
      *(bf16x4*)&As[0][nt * 16 + l16][wave * 16 + quad * 4] = pk;
    }
    __syncthreads();
    const int e   = tid >> 2;           // 0..63 (col within tile)
    const int seg = tid & 3;            // 16-l chunk
    const int ge  = col0 + e;
    const int hh  = ge >> 5;
    const int d   = ge & (HDIM - 1);
    const int bidx = row0 >> 12;
    const int l0   = row0 & (SEQ - 1);
    size_t dstbase = ((size_t)(bidx * HEADS + hh) * HDIM + d) * SEQ + l0 + seg * 16;
    bf16x8 t0 = *(const bf16x8*)&As[0][e][seg * 16];
    bf16x8 t1 = *(const bf16x8*)&As[0][e][seg * 16 + 8];
    *(bf16x8*)&vt[dstbase]     = t0;
    *(bf16x8*)&vt[dstbase + 8] = t1;
  }
}

// ---------------------------------------------------------------------------
// Flash attention v12 — v8 structure + staging bank-conflict fix ONLY.
//  Evidence: SQ_LDS_BANK_CONFLICT = 16.9M ≈ 35% of attn cycles.  Bank audit
//  (dword bank = byte/4 mod 32, per 16-lane phase): frag reads and the Pa
//  round-trip are ~free (2 lanes/bank); the conflicts are the staging
//  ds_write_b128: K-phase banks = 4*(r%8) with r spanning 4 values (4-way),
//  V-phase banks = 4*d with d in {0,1} (8-way).
//  FIX (rule #21, both-sides-or-neither): involution slot -> slot ^
//  ((slot>>4)<<1) applied to the Ks/Vs slot index at BOTH the staging write
//  and the fragment read.  K write phase becomes r^2qq (2 lanes/bank, free);
//  V write phase becomes d^2(sg&3) (free); reads remain per-phase
//  permutations of linear (free).  GLOBAL addresses untouched (unlike v10,
//  which also permuted the global source and failed).  Pa round-trip,
//  grid, block: byte-identical to the passing v8.
// ---------------------------------------------------------------------------
__global__ __launch_bounds__(512, 4) void attn_kernel(
    const bf16* __restrict__ Q, const bf16* __restrict__ K,
    const bf16* __restrict__ Vt, bf16* __restrict__ H)
{
  __shared__ alignas(16) bf16 Ks[2][4][64][8];   // [buf][frag][slot][8]
  __shared__ alignas(16) bf16 Vs[2][4][64][8];   // [buf][frag][slot][8]
  __shared__ alignas(16) bf16 Pa[8][16][72];     // per-wave P tile [q][key]

  const int tid  = threadIdx.x;
  const int wave = tid >> 6;
  const int lane = tid & 63;
  const int quad = lane >> 4;
  const int l16  = lane & 15;

  const int id = blockIdx.x;                     // 0..511
  const int bh = ((id & 7) << 1) | (id >> 8);    // XCD-local heads (2/XCD)
  const int q0 = ((id >> 3) & 31) * 128 + wave * 16;  // wave's 16 q rows

  const bf16* Qg = Q  + (size_t)bh * SEQ * HDIM;
  const bf16* Kg = K  + (size_t)bh * SEQ * HDIM;
  const bf16* Vg = Vt + (size_t)bh * HDIM * SEQ;

  // Q fragment (B-operand): n = l16 (q row), k = quad*8+j (dim)
  bf16x8 qf = *(const bf16x8*)&Qg[(size_t)(q0 + l16) * HDIM + quad * 8];

  f32x4 o0 = {0.f,0.f,0.f,0.f};
  f32x4 o1 = {0.f,0.f,0.f,0.f};
  float lsum = 0.f;

  // ---- staging role: threads 0-255 stage K, 256-511 stage V.
  //      Each thread: one 16B global load + one ds_write_b128 per tile.
  //      Slot index XOR-swizzled (slot ^ ((slot>>4)<<1)) on write AND read.
  const bool isK = tid < 256;
  const int  tt  = tid & 255;
  const bf16* sbase;
  size_t sstep;
  bf16* d0;
  if (isK) {
    const int r  = tt >> 2;            // key row in tile 0..63
    const int qq = tt & 3;             // dim quarter
    sbase = Kg + (size_t)r * HDIM + qq * 8;
    sstep = (size_t)64 * HDIM;         // next tile: +64 key rows
    const int slot = (qq * 16 + (r & 15)) ^ (qq << 1);
    d0 = &Ks[0][r >> 4][slot][0];
  } else {
    const int d  = tt >> 3;            // dim row 0..31
    const int sg = tt & 7;             // key segment (8 keys)
    sbase = Vg + (size_t)d * SEQ + sg * 8;
    sstep = 64;                        // next tile: +64 keys
    const int slot = ((sg & 3) * 16 + (d & 15)) ^ ((sg & 3) << 1);
    d0 = &Vs[0][((d >> 4) << 1) | (sg >> 2)][slot][0];
  }
  bf16* d1 = d0 + 4 * 64 * 8;          // buf1 slice of the same array

  // read-side swizzled slot: lane = quad*16+l16 -> lane ^ (quad<<1)
  const int lsw = lane ^ ((lane >> 4) << 1);

  const f32x4 minit = {-12.f,-12.f,-12.f,-12.f};   // fixed softmax max

  // ---- prologue: stage tile 0 into buf0 ----
  *(bf16x8*)d0 = *(const bf16x8*)sbase;
  __syncthreads();

  for (int t = 0; t < 64; ++t) {
    const int cur = t & 1;
    const int tn  = (t < 63) ? t + 1 : 63;   // last iter: harmless re-stage
    // ---- issue next-tile global load FIRST (completes under compute) ----
    bf16x8 g = *(const bf16x8*)&sbase[(size_t)tn * sstep];

    const bf16* KT = &Ks[cur][0][0][0];
    const bf16* VT = &Vs[cur][0][0][0];

    // ---- K fragments from LDS (swizzled slot: conflict-free) ----
    bf16x8 kf0 = *(const bf16x8*)&KT[(0 * 64 + lsw) * 8];
    bf16x8 kf1 = *(const bf16x8*)&KT[(1 * 64 + lsw) * 8];
    bf16x8 kf2 = *(const bf16x8*)&KT[(2 * 64 + lsw) * 8];
    bf16x8 kf3 = *(const bf16x8*)&KT[(3 * 64 + lsw) * 8];

    // ---- S^T = K Q^T - 12 : col = q (l16), rows = 4 consecutive keys ----
    f32x4 s[4];
    s[0] = __builtin_amdgcn_mfma_f32_16x16x32_bf16(kf0, qf, minit, 0, 0, 0);
    s[1] = __builtin_amdgcn_mfma_f32_16x16x32_bf16(kf1, qf, minit, 0, 0, 0);
    s[2] = __builtin_amdgcn_mfma_f32_16x16x32_bf16(kf2, qf, minit, 0, 0, 0);
    s[3] = __builtin_amdgcn_mfma_f32_16x16x32_bf16(kf3, qf, minit, 0, 0, 0);

    // ---- V^T fragments from LDS (swizzled slot) ----
    bf16x8 vf0 = *(const bf16x8*)&VT[(0 * 64 + lsw) * 8];
    bf16x8 vf1 = *(const bf16x8*)&VT[(1 * 64 + lsw) * 8];
    bf16x8 vf2 = *(const bf16x8*)&VT[(2 * 64 + lsw) * 8];
    bf16x8 vf3 = *(const bf16x8*)&VT[(3 * 64 + lsw) * 8];

    // ---- softmax numerators + packed P store + per-lane row-sum ----
    //      (textually identical to the verified v3/v5/v8 round-trip)
#pragma unroll
    for (int nt = 0; nt < 4; ++nt) {
      float p0 = fast_exp2(s[nt][0]);
      float p1 = fast_exp2(s[nt][1]);
      float p2 = fast_exp2(s[nt][2]);
      float p3 = fast_exp2(s[nt][3]);
      lsum += (p0 + p1) + (p2 + p3);
      bf16x4 pk;
      pk.x = (bf16)p0; pk.y = (bf16)p1; pk.z = (bf16)p2; pk.w = (bf16)p3;
      *(bf16x4*)&Pa[wave][l16][nt * 16 + quad * 4] = pk;   // ds_write_b64
    }

    // wave-internal LDS round trip (DS in-order per wave; drain before read)
    asm volatile("s_waitcnt lgkmcnt(0)" ::: "memory");

    // ---- O += P V : A = P[q][key], B = V^T[d][key] ----
    bf16x8 pf0 = *(const bf16x8*)&Pa[wave][l16][quad * 8];
    bf16x8 pf1 = *(const bf16x8*)&Pa[wave][l16][32 + quad * 8];
    o0 = __builtin_amdgcn_mfma_f32_16x16x32_bf16(pf0, vf0, o0, 0, 0, 0);
    o0 = __builtin_amdgcn_mfma_f32_16x16x32_bf16(pf1, vf1, o0, 0, 0, 0);
    o1 = __builtin_amdgcn_mfma_f32_16x16x32_bf16(pf0, vf2, o1, 0, 0, 0);
    o1 = __builtin_amdgcn_mfma_f32_16x16x32_bf16(pf1, vf3, o1, 0, 0, 0);

    // ---- write staged data into the other buffer, then fence the tile ----
    *(bf16x8*)(cur ? d0 : d1) = g;
    __syncthreads();
  }

  // ---- reduce row-sums across quads: lsum(lane) = total for q = l16 ----
  lsum += __shfl_xor(lsum, 16);
  lsum += __shfl_xor(lsum, 32);

  const int b = bh >> 3;
  const int h = bh & 7;
#pragma unroll
  for (int r = 0; r < 4; ++r) {
    float tot  = __shfl(lsum, quad * 4 + r);   // lane with l16 == quad*4+r
    float invr = 1.0f / tot;
    int   qg   = q0 + quad * 4 + r;
    size_t base = ((size_t)(b * SEQ + qg)) * EMBED + h * HDIM;
    H[base + l16]      = (bf16)(o0[r] * invr);
    H[base + 16 + l16] = (bf16)(o1[r] * invr);
  }
}

// ---------------------------------------------------------------------------
// Output projection: out = H @ Wo^T + bo   (fp32 out)  — unchanged from the
// passing round-13 build (double-buffered K-loop).
// ---------------------------------------------------------------------------
__global__ __launch_bounds__(256, 4) void out_proj_kernel(
    const bf16* __restrict__ Hm, const float* __restrict__ W,
    const float* __restrict__ bias, float* __restrict__ out)
{
  __shared__ alignas(16) bf16 As[2][64][72];
  __shared__ alignas(16) bf16 Bs[2][64][72];
  const int tid  = threadIdx.x;
  const int wave = tid >> 6;
  const int lane = tid & 63;
  const int quad = lane >> 4;
  const int l16  = lane & 15;
  const int row0 = blockIdx.x * 64;
  const int col0 = blockIdx.y * 64;

  // staging coordinates
  const int ar = tid >> 3;            // A: row 0..31 (p adds 32), col (tid&7)*8
  const int ac = (tid & 7) * 8;
  const int br = tid >> 4;            // B: row 0..15 (p adds 16), col (tid&15)*4
  const int bc = (tid & 15) * 4;

  f32x4 acc[4] = { {0.f,0.f,0.f,0.f},{0.f,0.f,0.f,0.f},
                   {0.f,0.f,0.f,0.f},{0.f,0.f,0.f,0.f} };

  // ---- prologue: stage K-tile 0 into buf0 ----
#pragma unroll
  for (int p = 0; p < 2; ++p) {
    int r = p * 32 + ar;
    *(bf16x8*)&As[0][r][ac] = *(const bf16x8*)&Hm[(size_t)(row0 + r) * EMBED + ac];
  }
#pragma unroll
  for (int p = 0; p < 4; ++p) {
    int r = p * 16 + br;
    float4 wv = *(const float4*)&W[(size_t)(col0 + r) * EMBED + bc];
    *(bf16x4*)&Bs[0][r][bc] = cvt4(wv);
  }
  __syncthreads();

#pragma unroll
  for (int it = 0; it < 4; ++it) {
    const int cur = it & 1;

    // ---- issue next K-tile's global loads FIRST (hide under MFMA) ----
    bf16x8 pa[2];
    float4 pw[4];
    if (it < 3) {
      const int kn = (it + 1) * 64;
#pragma unroll
      for (int p = 0; p < 2; ++p) {
        int r = p * 32 + ar;
        pa[p] = *(const bf16x8*)&Hm[(size_t)(row0 + r) * EMBED + kn + ac];
      }
#pragma unroll
      for (int p = 0; p < 4; ++p) {
        int r = p * 16 + br;
        pw[p] = *(const float4*)&W[(size_t)(col0 + r) * EMBED + kn + bc];
      }
    }

    // ---- compute current tile from LDS ----
#pragma unroll
    for (int kk = 0; kk < 2; ++kk) {
      bf16x8 a = *(const bf16x8*)&As[cur][wave * 16 + l16][kk * 32 + quad * 8];
#pragma unroll
      for (int nt = 0; nt < 4; ++nt) {
        bf16x8 b = *(const bf16x8*)&Bs[cur][nt * 16 + l16][kk * 32 + quad * 8];
        acc[nt] = __builtin_amdgcn_mfma_f32_16x16x32_bf16(a, b, acc[nt], 0, 0, 0);
      }
    }

    // ---- write staged regs into the other buffer, single barrier ----
    if (it < 3) {
#pragma unroll
      for (int p = 0; p < 2; ++p) {
        int r = p * 32 + ar;
        *(bf16x8*)&As[cur ^ 1][r][ac] = pa[p];
      }
#pragma unroll
      for (int p = 0; p < 4; ++p) {
        int r = p * 16 + br;
        *(bf16x4*)&Bs[cur ^ 1][r][bc] = cvt4(pw[p]);
      }
      __syncthreads();
    }
  }

#pragma unroll
  for (int nt = 0; nt < 4; ++nt) {
#pragma unroll
    for (int r = 0; r < 4; ++r) {
      int row = row0 + wave * 16 + quad * 4 + r;
      int col = col0 + nt * 16 + l16;
      out[(size_t)row * EMBED + col] = acc[nt][r] + bias[col];
    }
  }
}

// ---------------------------------------------------------------------------
extern "C" void kernel_launch(void* const* d_in, const int* in_sizes, int n_in,
                              void* d_out, int out_size, void* d_ws, size_t ws_size,
                              hipStream_t stream) {
  (void)in_sizes; (void)n_in; (void)out_size; (void)ws_size;
  const float* q  = (const float*)d_in[0];
  const float* k  = (const float*)d_in[1];
  const float* v  = (const float*)d_in[2];
  const float* Wq = (const float*)d_in[3];
  const float* bq = (const float*)d_in[4];
  const float* Wk = (const float*)d_in[5];
  const float* bk = (const float*)d_in[6];
  const float* Wv = (const float*)d_in[7];
  const float* bv = (const float*)d_in[8];
  const float* Wo = (const float*)d_in[9];
  const float* bo = (const float*)d_in[10];
  float* out = (float*)d_out;

  const size_t headElems = (size_t)BH * SEQ * HDIM;   // 2,097,152
  bf16* qh = (bf16*)d_ws;
  bf16* kh = qh + headElems;
  bf16* vt = kh + headElems;                          // [BH][HDIM][SEQ]
  bf16* Hm = vt + headElems;                          // [8192][256]

  // Q pre-scale: (1/sqrt(32)) * log2(e) -> softmax in exp2 domain.
  const float qs = 0.2550436604f;

  proj_kernel<<<dim3(128, 4, 3), dim3(256), 0, stream>>>(q, k, v, Wq, bq, Wk, bk,
                                                         Wv, bv, qh, kh, vt, qs);
  attn_kernel<<<dim3(512), dim3(512), 0, stream>>>(qh, kh, vt, Hm);
  out_proj_kernel<<<dim3(128, 4), dim3(256), 0, stream>>>(Hm, Wo, bo, out);
}